// Round 2
// baseline (130.525 us; speedup 1.0000x reference)
//
#include <hip/hip_runtime.h>

// Fused kernelized attention w/ Toeplitz topological mask, MI355X gfx950.
// B=8 H=12 L=577 (24x24 grid + CLS) D=64, fp32 I/O (runtime-probed vs bf16).
//
// out[b,q,h,:] = sum_k p(q,k) v[k,:] / sum_k p(q,k)
//   p = (relu(q)/8+eps)·(relu(k)+eps) * |mask(h,q,k)| + eps
//
// R6: traffic-focused.
//  - K' precompute DROPPED: main kernel reg-stages raw K (fp32->relu+eps->bf16)
//    into the XOR-swizzled LDS tile itself; the 10 q-tile blocks sharing (b,h)
//    are XCD-colocated so raw K is fetched from HBM once per (b,h).
//  - prep kernel keeps only V^T (needs cross-row transpose) and M (shared
//    across all 8 b's).
//  - main-grid slot map is h-major chunked across XCDs: each h's 80 blocks
//    span <=2 XCDs -> M tile fetched ~1.3x instead of ~4x from HBM; (b,h)
//    groups of 10 stay contiguous (never cross a 120-slot XCD chunk).
//  - 2-phase pipeline: K-loads + V^T global_load_lds issued before compute,
//    K convert+ds_write after GEMM2, one barrier per step.

#define Lq 577
#define NH 12
#define NB 8
#define DD 64
#define PAR 2304
#define EPSf 1e-8f

// workspace layout (bytes)
#define MM_OFF 7864320ull     // V^T = 8*12*64*640*2 = 7,864,320
                              // + M = 12*577*640*2  = 8,862,720  (total 16.7 MB)

// prep grid partition
#define PVT_BLOCKS 960        // V^T: 10 kt * 12 h * 8 b
#define PM_BLOCKS  2316       // M:   12 h * 193 (3 q-rows per block)

typedef __attribute__((ext_vector_type(4))) float f32x4;
typedef __attribute__((ext_vector_type(8))) short s16x8;

__device__ __forceinline__ float bflo(unsigned int u) {
    return __builtin_bit_cast(float, u << 16);
}
__device__ __forceinline__ float bfhi(unsigned int u) {
    return __builtin_bit_cast(float, u & 0xffff0000u);
}
// float -> bf16 round-to-nearest-even
__device__ __forceinline__ unsigned int f2bf(float f) {
    unsigned int x = __builtin_bit_cast(unsigned int, f);
    return (x + 0x7fffu + ((x >> 16) & 1u)) >> 16;
}
__device__ __forceinline__ int imin(int a, int b) { return a < b ? a : b; }

// async global->LDS, 16B per lane; lds dest = wave-uniform base + lane*16
__device__ __forceinline__ void gload_lds16(const unsigned short* g, unsigned short* l) {
    __builtin_amdgcn_global_load_lds(
        (const __attribute__((address_space(1))) unsigned int*)g,
        (__attribute__((address_space(3))) unsigned int*)l, 16, 0, 0);
}

// per-wave dtype probe: fp32 N(0,1) lands in (2^-12, 64); bf16-pair
// reinterpretation lands at ~2^+-100 / denormal. Works for partial waves.
__device__ __forceinline__ bool probe_f32(const void* Qg) {
    float x = fabsf(((const float*)Qg)[threadIdx.x]);
    unsigned long long hit = __ballot(x > 2.44140625e-4f && x < 64.0f);
    unsigned long long act = __ballot(1);
    return 2 * __popcll(hit) >= __popcll(act);
}

// 8 consecutive elements -> float, dtype-templated
template <bool F32>
__device__ __forceinline__ void load8f(const void* G, size_t eidx, float* o) {
    if constexpr (F32) {
        const float* p = (const float*)G + eidx;
        float4 a = *(const float4*)p;
        float4 b = *(const float4*)(p + 4);
        o[0] = a.x; o[1] = a.y; o[2] = a.z; o[3] = a.w;
        o[4] = b.x; o[5] = b.y; o[6] = b.z; o[7] = b.w;
    } else {
        const unsigned short* p = (const unsigned short*)G + eidx;
        uint4 a = *(const uint4*)p;
        unsigned int u[4] = {a.x, a.y, a.z, a.w};
#pragma unroll
        for (int j = 0; j < 4; ++j) {
            o[2 * j]     = bflo(u[j]);
            o[2 * j + 1] = bfhi(u[j]);
        }
    }
}

// ---------------- prep kernel: V^T | M, split by blockIdx range
template <bool F32>
__device__ void prep_all_body(const void* __restrict__ Vg,
                              const void* __restrict__ Tg,
                              unsigned short* __restrict__ Vt,
                              unsigned short* __restrict__ Mm,
                              unsigned short* s) {
    const int bid = blockIdx.x;
    const int t   = threadIdx.x;

    if (bid < PVT_BLOCKS) {
        // ---- role 1: V^T bf16 [b,h,d,640], zeros past k=576
        int r  = bid;
        int kt = r % 10; r /= 10;
        int h  = r % NH;
        int b  = r / NH;
        {
            int kl  = t >> 2;              // 0..63
            int dch = (t & 3) * 16;
            int k   = kt * 64 + kl;
            unsigned int pk[8] = {};
            if (k <= 576) {
                float f[16];
                size_t base = ((size_t)((b * Lq + k) * NH + h)) * DD + dch;
                load8f<F32>(Vg, base, f);
                load8f<F32>(Vg, base + 8, f + 8);
#pragma unroll
                for (int j = 0; j < 8; ++j)
                    pk[j] = f2bf(f[2 * j]) | (f2bf(f[2 * j + 1]) << 16);
            }
#pragma unroll
            for (int j = 0; j < 8; ++j)
                *(unsigned int*)&s[kl * 72 + dch + 2 * j] = pk[j];
        }
        __syncthreads();
        {
            int d   = t >> 2;
            int kch = (t & 3) * 16;
            unsigned int o[8];
#pragma unroll
            for (int j = 0; j < 8; ++j) {
                unsigned short v0 = s[(kch + 2 * j) * 72 + d];
                unsigned short v1 = s[(kch + 2 * j + 1) * 72 + d];
                o[j] = (unsigned int)v0 | ((unsigned int)v1 << 16);
            }
            size_t base = ((size_t)((b * NH + h) * 64 + d)) * 640 + kt * 64 + kch;
            *(uint4*)(Vt + base)     = make_uint4(o[0], o[1], o[2], o[3]);
            *(uint4*)(Vt + base + 8) = make_uint4(o[4], o[5], o[6], o[7]);
        }

    } else {
        // ---- role 2: M = |toeplitz mask| bf16 [h,q,640]; 3 q-rows / block
        int r  = bid - PVT_BLOCKS;
        int h  = r / 193;
        int qb = (r % 193) * 3;
        if (t < 240) {
            int q = qb + t / 80;
            if (q < Lq) {
                int k0 = (t % 80) * 8;
                int cq = 0;
                if (q > 0) {
                    int qq = q - 1;
                    int qi = (qq * 2731) >> 16;           // floor(qq/24)
                    cq = qq + 24 * qi + 1176;
                }
                unsigned int o[4];
#pragma unroll
                for (int j = 0; j < 4; ++j) {
                    unsigned int hv[2];
#pragma unroll
                    for (int e = 0; e < 2; ++e) {
                        int k = k0 + 2 * j + e;
                        float m;
                        if (k > 576) m = 0.0f;
                        else if (k == 0 || q == 0) m = 1.0f;
                        else {
                            int kk = k - 1;
                            int ki = (kk * 2731) >> 16;
                            int idx = cq - (kk + 24 * ki);
                            float pv = F32 ? ((const float*)Tg)[h * PAR + idx]
                                           : bflo((unsigned int)((const unsigned short*)Tg)[h * PAR + idx]);
                            m = fabsf(pv);
                            m = (m == m) ? m : 0.0f;
                        }
                        hv[e] = f2bf(m);
                    }
                    o[j] = hv[0] | (hv[1] << 16);
                }
                *(uint4*)(Mm + (size_t)(h * Lq + q) * 640 + k0) = make_uint4(o[0], o[1], o[2], o[3]);
            }
        }
    }
}
__global__ __launch_bounds__(256)
void prep_all(const void* __restrict__ Qg, const void* __restrict__ Vg,
              const void* __restrict__ Tg,
              unsigned short* __restrict__ Vt, unsigned short* __restrict__ Mm) {
    __shared__ __align__(16) unsigned short s[64 * 72];   // used by role 1 only
    if (probe_f32(Qg)) prep_all_body<true>(Vg, Tg, Vt, Mm, s);
    else               prep_all_body<false>(Vg, Tg, Vt, Mm, s);
}

// ---------------- main kernel
template <bool F32>
__device__ void attn_body(const void* __restrict__ Qg,
                          const void* __restrict__ Kg,
                          const unsigned short* __restrict__ Vt,
                          const unsigned short* __restrict__ Mm,
                          void* __restrict__ Og,
                          unsigned short* s_k, unsigned short* s_vt,
                          unsigned short* s_p_all) {
    const int tid  = threadIdx.x;
    const int w    = tid >> 6;
    const int lane = tid & 63;
    const int g    = lane >> 4;   // quad
    const int lm   = lane & 15;

    // h-major chunked XCD slot map (bid%8 = XCD under round-robin dispatch):
    //   slot 0..119 -> XCD0, 120..239 -> XCD1, ...
    //   h group = 80 contiguous slots (spans <=2 XCDs -> M ~1.3x HBM);
    //   (b,h) group = 10 contiguous slots, 120%10==0 -> never crosses an XCD.
    const int bid  = blockIdx.x;
    const int slot = (bid & 7) * 120 + (bid >> 3);
    const int h    = slot / 80;
    const int rem  = slot - h * 80;
    const int b    = rem / 10;
    const int qt   = rem - b * 10;

    unsigned short* s_pw = s_p_all + w * 16 * 64;   // wave-private P tile [16][64] (XOR-swz)
    const int q0w = qt * 64 + w * 16;               // wave's first q row

    // ---- Q B-frags in registers: lane holds Q[q0w+lm][ds*32+g*8+j]
    const int q  = q0w + lm;
    const int qc = imin(q, Lq - 1);
    s16x8 a_q[2];
    {
        size_t rbase = ((size_t)((b * Lq + qc) * NH + h)) * DD;
#pragma unroll
        for (int ds = 0; ds < 2; ++ds) {
            float f[8];
            load8f<F32>(Qg, rbase + ds * 32 + g * 8, f);
            s16x8 a;
#pragma unroll
            for (int j = 0; j < 8; ++j) {
                float v = fmaf(fmaxf(f[j], 0.0f), 0.125f, EPSf);  // relu/8+eps
                a[j] = (short)f2bf(v);
            }
            a_q[ds] = a;
        }
    }

    // ---- staging lane constants
    const int r8 = lane >> 3;          // V^T: row within 8-row group
    const int c8 = lane & 7;           // V^T: 16B chunk within row
    const int xr = (c8 ^ r8) * 8;      // XOR-swizzled source chunk (elements)
    const int rl = lane >> 2;          // K: row within wave's 16-row group
    const int cc = lane & 3;           // K: 16-float column chunk

    const unsigned short* VtL0 = Vt + ((size_t)(b * NH + h) * 64 + (w * 16 + r8)) * 640 + xr;
    const unsigned short* VtL1 = VtL0 + 8 * 640;
    // M row for THIS lane's q (per-lane register loads; 32B segments, L2-hot)
    const unsigned short* MmQ  = Mm + (size_t)h * (Lq * 640) + (size_t)qc * 640 + g * 4;

    f32x4 o_acc[4] = {};   // [df] C-frags: rows q_local=g*4+r, cols d=df*16+lm
    float rs = 0.0f;       // per-lane partial row sum for q (this quad's k subset)
    const int x7 = lm & 7; // fragment-read swizzle key

    // V^T tile -> LDS buffer (async, linear dest + pre-swizzled source)
    auto stageV = [&](int kb, int buf) {
        unsigned short* svb = s_vt + buf * 4096 + (w * 16) * 64;
        gload_lds16(VtL0 + kb, svb);
        gload_lds16(VtL1 + kb, svb + 8 * 64);
    };
    // raw K rows (fp32/bf16) -> 16 floats in regs; wave stages its 16 rows
    auto loadK = [&](int kbn, float* f) {
        int kcl = imin(kbn + w * 16 + rl, Lq - 1);
        size_t base = ((size_t)((b * Lq + kcl) * NH + h)) * DD + cc * 16;
        load8f<F32>(Kg, base, f);
        load8f<F32>(Kg, base + 8, f + 8);
    };
    // relu+eps -> bf16 -> swizzled LDS (chunk ^= row&7); 2x ds_write_b128
    auto writeK = [&](int buf, const float* f) {
        unsigned short* skb = s_k + buf * 4096;
        const int R  = w * 16 + rl;
        const int r7 = R & 7;
        unsigned int o[8];
#pragma unroll
        for (int j = 0; j < 8; ++j) {
            unsigned int lo = f2bf(fmaxf(f[2 * j], 0.0f) + EPSf);
            unsigned int hi = f2bf(fmaxf(f[2 * j + 1], 0.0f) + EPSf);
            o[j] = lo | (hi << 16);
        }
        *(uint4*)(skb + R * 64 + (((2 * cc) ^ r7) << 3))     = make_uint4(o[0], o[1], o[2], o[3]);
        *(uint4*)(skb + R * 64 + (((2 * cc + 1) ^ r7) << 3)) = make_uint4(o[4], o[5], o[6], o[7]);
    };

    // prologue: fill buffer 0
    {
        float k0r[16];
        loadK(0, k0r);
        stageV(0, 0);
        writeK(0, k0r);
    }
    __syncthreads();   // drains vmcnt+lgkm -> buf0 ready

    for (int t = 0; t < 10; ++t) {
        const int kb  = t * 64;
        const int buf = t & 1;

        // M for THIS step -> regs (latency hides under GEMM1)
        uint2 mu[4];
#pragma unroll
        for (int cf = 0; cf < 4; ++cf)
            mu[cf] = *(const uint2*)(MmQ + kb + cf * 16);

        // prefetch NEXT tile: raw K -> regs, V^T -> other LDS buffer
        float kn[16];
        if (t < 9) {
            loadK(kb + 64, kn);
            stageV(kb + 64, buf ^ 1);
        }

        const unsigned short* skB = s_k  + buf * 4096;
        const unsigned short* svB = s_vt + buf * 4096;

        // ---- GEMM1 (transposed): S^T[64k x 16q] = K' · Q^T
        f32x4 sf[4];
#pragma unroll
        for (int cf = 0; cf < 4; ++cf) {
            const unsigned short* skr = skB + (cf * 16 + lm) * 64;
            int co = (g ^ x7) * 8;
            s16x8 kf0 = *(const s16x8*)(skr + co);
            s16x8 kf1 = *(const s16x8*)(skr + (co ^ 32));
            f32x4 acc = {};
            acc = __builtin_amdgcn_mfma_f32_16x16x32_bf16(kf0, a_q[0], acc, 0, 0, 0);
            acc = __builtin_amdgcn_mfma_f32_16x16x32_bf16(kf1, a_q[1], acc, 0, 0, 0);
            sf[cf] = acc;   // reg r: k_local = cf*16 + g*4 + r, q = q0w + lm
        }

        // ---- p = max(s,0)*m + eps; row-sum; pack 4 -> b64 wave-private LDS
        //      write chunk (cf*2+(g>>1))^x7, half (g&1)  [XOR swizzle, row=lm]
#pragma unroll
        for (int cf = 0; cf < 4; ++cf) {
            float m0 = bflo(mu[cf].x), m1 = bfhi(mu[cf].x);
            float m2 = bflo(mu[cf].y), m3 = bfhi(mu[cf].y);
            float p0 = fmaf(fmaxf(sf[cf][0], 0.0f), m0, EPSf);
            float p1 = fmaf(fmaxf(sf[cf][1], 0.0f), m1, EPSf);
            float p2 = fmaf(fmaxf(sf[cf][2], 0.0f), m2, EPSf);
            float p3 = fmaf(fmaxf(sf[cf][3], 0.0f), m3, EPSf);
            rs += (p0 + p1) + (p2 + p3);
            unsigned int d0 = f2bf(p0) | (f2bf(p1) << 16);
            unsigned int d1 = f2bf(p2) | (f2bf(p3) << 16);
            int pc = (((cf * 2 + (g >> 1)) ^ x7) << 3) + ((g & 1) << 2);
            *(uint2*)&s_pw[lm * 64 + pc] = make_uint2(d0, d1);
        }
        // no barrier: s_pw wave-private; in-order DS pipe orders write->read

        // ---- GEMM2: O[16q x 64d] += P · V   (read chunk (ks*4+g)^x7)
#pragma unroll
        for (int ks = 0; ks < 2; ++ks) {
            s16x8 pa = *(const s16x8*)&s_pw[lm * 64 + (((ks * 4 + g) ^ x7) << 3)];
#pragma unroll
            for (int df = 0; df < 4; ++df) {
                const unsigned short* svr = svB + (df * 16 + lm) * 64;
                s16x8 vb = *(const s16x8*)(svr + (((ks * 4 + g) ^ x7) << 3));
                o_acc[df] = __builtin_amdgcn_mfma_f32_16x16x32_bf16(pa, vb, o_acc[df], 0, 0, 0);
            }
        }

        // convert+write NEXT K tile into the idle buffer (loads have had the
        // whole compute phase to land), then one barrier per step
        if (t < 9) {
            writeK(buf ^ 1, kn);
            __syncthreads();
        }
    }
    // note: k in [577,640) contributes m=0, V^T=0 -> only +63*eps on rs (negligible)

    // ---- total row sum for q = q0w+lm: combine the 4 quad partials
    float tot = rs;
    tot += __shfl_xor(tot, 16, 64);
    tot += __shfl_xor(tot, 32, 64);
    float inv = (tot > 0.0f) ? 1.0f / tot : 0.0f;

    // ---- epilogue: rows q = q0w + g*4 + r; fetch inv from lane (g*4+r)
#pragma unroll
    for (int r = 0; r < 4; ++r) {
        int   qrow  = q0w + g * 4 + r;
        float inv_r = __shfl(inv, g * 4 + r, 64);
        if (qrow < Lq) {
            size_t base = ((size_t)((b * Lq + qrow) * NH + h)) * DD;
#pragma unroll
            for (int df = 0; df < 4; ++df) {
                float val = o_acc[df][r] * inv_r;
                if constexpr (F32)
                    ((float*)Og)[base + df * 16 + lm] = val;
                else
                    ((unsigned short*)Og)[base + df * 16 + lm] = (unsigned short)f2bf(val);
            }
        }
    }
}

__global__ __launch_bounds__(256, 4)
void fused_topo_attn(const void* __restrict__ Qg,
                     const void* __restrict__ Kg,
                     const unsigned short* __restrict__ Vt,
                     const unsigned short* __restrict__ Mm,
                     void* __restrict__ Og) {
    // 40,960 B total = 160KB/4 exactly -> 4 blocks/CU
    __shared__ __align__(16) unsigned short s_k[2 * 64 * 64];   // 16384 B (dbuf, swizzled)
    __shared__ __align__(16) unsigned short s_vt[2 * 64 * 64];  // 16384 B (dbuf, swizzled)
    __shared__ __align__(16) unsigned short s_p[4 * 16 * 64];   //  8192 B (XOR-swz, no pad)

    if (probe_f32(Qg)) attn_body<true>(Qg, Kg, Vt, Mm, Og, s_k, s_vt, s_p);
    else               attn_body<false>(Qg, Kg, Vt, Mm, Og, s_k, s_vt, s_p);
}

extern "C" void kernel_launch(void* const* d_in, const int* in_sizes, int n_in,
                              void* d_out, int out_size, void* d_ws, size_t ws_size,
                              hipStream_t stream) {
    (void)in_sizes; (void)n_in; (void)out_size; (void)ws_size;
    unsigned short* Vt = (unsigned short*)d_ws;
    unsigned short* Mm = (unsigned short*)((char*)d_ws + MM_OFF);

    prep_all<<<PVT_BLOCKS + PM_BLOCKS, 256, 0, stream>>>(
        d_in[0], d_in[2], d_in[3], Vt, Mm);
    fused_topo_attn<<<960, 256, 0, stream>>>(d_in[0], d_in[1], Vt, Mm, d_out);
}

// Round 4
// 126.867 us; speedup vs baseline: 1.0288x; 1.0288x over previous
//
#include <hip/hip_runtime.h>

// Fused kernelized attention w/ Toeplitz topological mask, MI355X gfx950.
// B=8 H=12 L=577 (24x24 grid + CLS) D=64, fp32 I/O (runtime-probed vs bf16).
//
// out[b,q,h,:] = sum_k p(q,k) v[k,:] / sum_k p(q,k)
//   p = (relu(q)/8+eps)·(relu(k)+eps) * |mask(h,q,k)| + eps
//
// R8: R7 minus the unsafe numerics. R7's post-timing failure isolated to
// v_cvt_pk_bf16_f32 (not RNE on gfx950 -> biased-low bf16 P vs exact f32
// denominator -> ~1e-2 output bias on the timing input set). Reverted to the
// hand RNE f2bf + fmax path that passed in R5/R6. Kept from R7 (all safe):
//  - K' conversion in prep (once), main stages K' via global_load_lds with
//    pre-swizzled source (no in-loop VALU conversion, no writeK conflicts).
//  - M per-lane in registers, ping-ponged one step ahead.
//  - h-major XCD slot map (M ~1.3x HBM instead of ~4x).
//  - single barrier/step, double-buffered LDS.

#define Lq 577
#define NH 12
#define NB 8
#define DD 64
#define PAR 2304
#define EPSf 1e-8f

// workspace layout (bytes)
#define VT_OFF 7090176ull     // K' = 3,545,088 elem * 2B
#define MM_OFF 14954496ull    // + V^T = 8*12*64*640*2 = 7,864,320
                              // + M   = 12*577*640*2  = 8,862,720  (total 23.8 MB)

// fused prep grid partition
#define PK_BLOCKS  1731       // K':  1731 * 2048 elems = |K|
#define PVT_BLOCKS 960        // V^T: 10 kt * 12 h * 8 b
#define PM_BLOCKS  2316       // M:   12 h * 193 (3 q-rows per block)

typedef __attribute__((ext_vector_type(4))) float f32x4;
typedef __attribute__((ext_vector_type(8))) short s16x8;

__device__ __forceinline__ float bflo(unsigned int u) {
    return __builtin_bit_cast(float, u << 16);
}
__device__ __forceinline__ float bfhi(unsigned int u) {
    return __builtin_bit_cast(float, u & 0xffff0000u);
}
// float -> bf16 round-to-nearest-even. NOTE (R7 lesson): do NOT replace with
// inline-asm v_cvt_pk_bf16_f32 — its rounding differs (biased), broke the
// post-timing check at 4.7e-2.
__device__ __forceinline__ unsigned int f2bf(float f) {
    unsigned int x = __builtin_bit_cast(unsigned int, f);
    return (x + 0x7fffu + ((x >> 16) & 1u)) >> 16;
}
__device__ __forceinline__ int imin(int a, int b) { return a < b ? a : b; }

// async global->LDS, 16B per lane; lds dest = wave-uniform base + lane*16
__device__ __forceinline__ void gload_lds16(const unsigned short* g, unsigned short* l) {
    __builtin_amdgcn_global_load_lds(
        (const __attribute__((address_space(1))) unsigned int*)g,
        (__attribute__((address_space(3))) unsigned int*)l, 16, 0, 0);
}

// per-wave dtype probe: fp32 N(0,1) lands in (2^-12, 64); bf16-pair
// reinterpretation lands at ~2^+-100 / denormal. Works for partial waves.
__device__ __forceinline__ bool probe_f32(const void* Qg) {
    float x = fabsf(((const float*)Qg)[threadIdx.x]);
    unsigned long long hit = __ballot(x > 2.44140625e-4f && x < 64.0f);
    unsigned long long act = __ballot(1);
    return 2 * __popcll(hit) >= __popcll(act);
}

// 8 consecutive elements -> float, dtype-templated
template <bool F32>
__device__ __forceinline__ void load8f(const void* G, size_t eidx, float* o) {
    if constexpr (F32) {
        const float* p = (const float*)G + eidx;
        float4 a = *(const float4*)p;
        float4 b = *(const float4*)(p + 4);
        o[0] = a.x; o[1] = a.y; o[2] = a.z; o[3] = a.w;
        o[4] = b.x; o[5] = b.y; o[6] = b.z; o[7] = b.w;
    } else {
        const unsigned short* p = (const unsigned short*)G + eidx;
        uint4 a = *(const uint4*)p;
        unsigned int u[4] = {a.x, a.y, a.z, a.w};
#pragma unroll
        for (int j = 0; j < 4; ++j) {
            o[2 * j]     = bflo(u[j]);
            o[2 * j + 1] = bfhi(u[j]);
        }
    }
}

// ---------------- fused prep kernel: K' | V^T | M, split by blockIdx range
template <bool F32>
__device__ void prep_all_body(const void* __restrict__ Kg,
                              const void* __restrict__ Vg,
                              const void* __restrict__ Tg,
                              unsigned short* __restrict__ Kp,
                              unsigned short* __restrict__ Vt,
                              unsigned short* __restrict__ Mm,
                              unsigned short* s) {
    const int bid = blockIdx.x;
    const int t   = threadIdx.x;

    if (bid < PK_BLOCKS) {
        // ---- role 1: K' = bf16(relu(K)+eps), layout [b,k,h,d]
        size_t i8 = ((size_t)bid * 256 + t) * 8;
        float f[8];
        load8f<F32>(Kg, i8, f);
        unsigned int o[4];
#pragma unroll
        for (int j = 0; j < 4; ++j) {
            unsigned int lo = f2bf(fmaxf(f[2 * j], 0.0f) + EPSf);
            unsigned int hi = f2bf(fmaxf(f[2 * j + 1], 0.0f) + EPSf);
            o[j] = lo | (hi << 16);
        }
        *(uint4*)(Kp + i8) = make_uint4(o[0], o[1], o[2], o[3]);

    } else if (bid < PK_BLOCKS + PVT_BLOCKS) {
        // ---- role 2: V^T bf16 [b,h,d,640], zeros past k=576
        int r  = bid - PK_BLOCKS;
        int kt = r % 10; r /= 10;
        int h  = r % NH;
        int b  = r / NH;
        {
            int kl  = t >> 2;              // 0..63
            int dch = (t & 3) * 16;
            int k   = kt * 64 + kl;
            unsigned int pk[8] = {};
            if (k <= 576) {
                float f[16];
                size_t base = ((size_t)((b * Lq + k) * NH + h)) * DD + dch;
                load8f<F32>(Vg, base, f);
                load8f<F32>(Vg, base + 8, f + 8);
#pragma unroll
                for (int j = 0; j < 8; ++j)
                    pk[j] = f2bf(f[2 * j]) | (f2bf(f[2 * j + 1]) << 16);
            }
#pragma unroll
            for (int j = 0; j < 8; ++j)
                *(unsigned int*)&s[kl * 72 + dch + 2 * j] = pk[j];
        }
        __syncthreads();
        {
            int d   = t >> 2;
            int kch = (t & 3) * 16;
            unsigned int o[8];
#pragma unroll
            for (int j = 0; j < 8; ++j) {
                unsigned short v0 = s[(kch + 2 * j) * 72 + d];
                unsigned short v1 = s[(kch + 2 * j + 1) * 72 + d];
                o[j] = (unsigned int)v0 | ((unsigned int)v1 << 16);
            }
            size_t base = ((size_t)((b * NH + h) * 64 + d)) * 640 + kt * 64 + kch;
            *(uint4*)(Vt + base)     = make_uint4(o[0], o[1], o[2], o[3]);
            *(uint4*)(Vt + base + 8) = make_uint4(o[4], o[5], o[6], o[7]);
        }

    } else {
        // ---- role 3: M = |toeplitz mask| bf16 [h,q,640]; 3 q-rows / block
        int r  = bid - (PK_BLOCKS + PVT_BLOCKS);
        int h  = r / 193;
        int qb = (r % 193) * 3;
        if (t < 240) {
            int q = qb + t / 80;
            if (q < Lq) {
                int k0 = (t % 80) * 8;
                int cq = 0;
                if (q > 0) {
                    int qq = q - 1;
                    int qi = (qq * 2731) >> 16;           // floor(qq/24)
                    cq = qq + 24 * qi + 1176;
                }
                unsigned int o[4];
#pragma unroll
                for (int j = 0; j < 4; ++j) {
                    unsigned int hv[2];
#pragma unroll
                    for (int e = 0; e < 2; ++e) {
                        int k = k0 + 2 * j + e;
                        float m;
                        if (k > 576) m = 0.0f;
                        else if (k == 0 || q == 0) m = 1.0f;
                        else {
                            int kk = k - 1;
                            int ki = (kk * 2731) >> 16;
                            int idx = cq - (kk + 24 * ki);
                            float pv = F32 ? ((const float*)Tg)[h * PAR + idx]
                                           : bflo((unsigned int)((const unsigned short*)Tg)[h * PAR + idx]);
                            m = fabsf(pv);
                            m = (m == m) ? m : 0.0f;
                        }
                        hv[e] = f2bf(m);
                    }
                    o[j] = hv[0] | (hv[1] << 16);
                }
                *(uint4*)(Mm + (size_t)(h * Lq + q) * 640 + k0) = make_uint4(o[0], o[1], o[2], o[3]);
            }
        }
    }
}
__global__ __launch_bounds__(256)
void prep_all(const void* __restrict__ Qg, const void* __restrict__ Kg,
              const void* __restrict__ Vg, const void* __restrict__ Tg,
              unsigned short* __restrict__ Kp, unsigned short* __restrict__ Vt,
              unsigned short* __restrict__ Mm) {
    __shared__ __align__(16) unsigned short s[64 * 72];   // used by role 2 only
    if (probe_f32(Qg)) prep_all_body<true>(Kg, Vg, Tg, Kp, Vt, Mm, s);
    else               prep_all_body<false>(Kg, Vg, Tg, Kp, Vt, Mm, s);
}

// ---------------- main kernel
template <bool F32>
__device__ void attn_body(const void* __restrict__ Qg,
                          const unsigned short* __restrict__ Kp,
                          const unsigned short* __restrict__ Vt,
                          const unsigned short* __restrict__ Mm,
                          void* __restrict__ Og,
                          unsigned short* s_k, unsigned short* s_vt,
                          unsigned short* s_p_all) {
    const int tid  = threadIdx.x;
    const int w    = tid >> 6;
    const int lane = tid & 63;
    const int g    = lane >> 4;   // quad
    const int lm   = lane & 15;

    // h-major chunked XCD slot map (bid%8 = XCD under round-robin dispatch):
    //   slot chunks of 120 per XCD; h group = 80 contiguous slots (<=2 XCDs
    //   -> M ~1.3x HBM); (b,h) group = 10 contiguous slots, never crosses
    //   a 120-boundary (120%10==0) -> K'/V^T L2-local.
    const int bid  = blockIdx.x;
    const int slot = (bid & 7) * 120 + (bid >> 3);
    const int h    = slot / 80;
    const int rem  = slot - h * 80;
    const int b    = rem / 10;
    const int qt   = rem - b * 10;

    unsigned short* s_pw = s_p_all + w * 16 * 64;   // wave-private P tile [16][64] (XOR-swz)
    const int q0w = qt * 64 + w * 16;               // wave's first q row

    // ---- Q B-frags in registers: lane holds Q[q0w+lm][ds*32+g*8+j]
    const int q  = q0w + lm;
    const int qc = imin(q, Lq - 1);
    s16x8 a_q[2];
    {
        size_t rbase = ((size_t)((b * Lq + qc) * NH + h)) * DD;
#pragma unroll
        for (int ds = 0; ds < 2; ++ds) {
            float f[8];
            load8f<F32>(Qg, rbase + ds * 32 + g * 8, f);
            s16x8 a;
#pragma unroll
            for (int j = 0; j < 8; ++j) {
                float v = fmaf(fmaxf(f[j], 0.0f), 0.125f, EPSf);  // relu/8+eps
                a[j] = (short)f2bf(v);
            }
            a_q[ds] = a;
        }
    }

    // ---- staging lane constants (XOR-swizzled source chunks)
    const int r8 = lane >> 3;          // row within 8-row group
    const int c8 = lane & 7;           // 16B chunk within row
    const int xr = (c8 ^ r8) * 8;      // logical element offset of this lane's chunk

    const unsigned short* KpBH = Kp + (size_t)b * (Lq * NH * DD) + h * DD;   // + k*768
    const unsigned short* VtL0 = Vt + ((size_t)(b * NH + h) * 64 + (w * 16 + r8)) * 640 + xr;
    const unsigned short* VtL1 = VtL0 + 8 * 640;
    // M row for THIS lane's q (per-lane register loads; 32B segments, L2-hot)
    const unsigned short* MmQ  = Mm + (size_t)h * (Lq * 640) + (size_t)qc * 640 + g * 4;

    f32x4 o_acc[4] = {};   // [df] C-frags: rows q_local=g*4+r, cols d=df*16+lm
    float rs = 0.0f;       // per-lane partial row sum for q (this quad's k subset)
    const int x7 = lm & 7; // fragment-read swizzle key

    // stage K'/V^T tile for column block kb into LDS buffer buf (4 x 1KB per wave)
    auto stageKV = [&](int kb, int buf) {
        unsigned short* skb = s_k  + buf * 4096 + (w * 16) * 64;
        unsigned short* svb = s_vt + buf * 4096 + (w * 16) * 64;
        int krr = kb + w * 16 + r8;
        int kr0 = imin(krr, Lq - 1);
        int kr1 = imin(krr + 8, Lq - 1);
        gload_lds16(KpBH + (size_t)kr0 * (NH * DD) + xr, skb);
        gload_lds16(KpBH + (size_t)kr1 * (NH * DD) + xr, skb + 8 * 64);
        gload_lds16(VtL0 + kb, svb);
        gload_lds16(VtL1 + kb, svb + 8 * 64);
    };

    // prologue: fill buffer 0; prime M ping-pong
    stageKV(0, 0);
    uint2 mu_n[4];
#pragma unroll
    for (int cf = 0; cf < 4; ++cf)
        mu_n[cf] = *(const uint2*)(MmQ + cf * 16);
    __syncthreads();   // drains vmcnt -> buf0 ready

    for (int t = 0; t < 10; ++t) {
        const int kb  = t * 64;
        const int buf = t & 1;

        // M for THIS step (prefetched last step); issue next step's M loads
        uint2 mu[4];
#pragma unroll
        for (int cf = 0; cf < 4; ++cf) mu[cf] = mu_n[cf];

        if (t < 9) {
            // prefetch NEXT tile into the other buffer + next M rows
            stageKV(kb + 64, buf ^ 1);
#pragma unroll
            for (int cf = 0; cf < 4; ++cf)
                mu_n[cf] = *(const uint2*)(MmQ + kb + 64 + cf * 16);
        }

        const unsigned short* skB = s_k  + buf * 4096;
        const unsigned short* svB = s_vt + buf * 4096;

        // ---- GEMM1 (transposed): S^T[64k x 16q] = K' · Q^T
        f32x4 sf[4];
#pragma unroll
        for (int cf = 0; cf < 4; ++cf) {
            const unsigned short* skr = skB + (cf * 16 + lm) * 64;
            int co = (g ^ x7) * 8;
            s16x8 kf0 = *(const s16x8*)(skr + co);
            s16x8 kf1 = *(const s16x8*)(skr + (co ^ 32));
            f32x4 acc = {};
            acc = __builtin_amdgcn_mfma_f32_16x16x32_bf16(kf0, a_q[0], acc, 0, 0, 0);
            acc = __builtin_amdgcn_mfma_f32_16x16x32_bf16(kf1, a_q[1], acc, 0, 0, 0);
            sf[cf] = acc;   // reg r: k_local = cf*16 + g*4 + r, q = q0w + lm
        }

        // ---- p = max(s,0)*m + eps; row-sum; hand-RNE pack -> b64 wave-private
        //      LDS. write chunk (cf*2+(g>>1))^x7, half (g&1) [XOR swz, row=lm]
#pragma unroll
        for (int cf = 0; cf < 4; ++cf) {
            float m0 = bflo(mu[cf].x), m1 = bfhi(mu[cf].x);
            float m2 = bflo(mu[cf].y), m3 = bfhi(mu[cf].y);
            float p0 = fmaf(fmaxf(sf[cf][0], 0.0f), m0, EPSf);
            float p1 = fmaf(fmaxf(sf[cf][1], 0.0f), m1, EPSf);
            float p2 = fmaf(fmaxf(sf[cf][2], 0.0f), m2, EPSf);
            float p3 = fmaf(fmaxf(sf[cf][3], 0.0f), m3, EPSf);
            rs += (p0 + p1) + (p2 + p3);
            unsigned int d0 = f2bf(p0) | (f2bf(p1) << 16);
            unsigned int d1 = f2bf(p2) | (f2bf(p3) << 16);
            int pc = (((cf * 2 + (g >> 1)) ^ x7) << 3) + ((g & 1) << 2);
            *(uint2*)&s_pw[lm * 64 + pc] = make_uint2(d0, d1);
        }
        // no barrier: s_pw wave-private; in-order DS pipe orders write->read

        // ---- GEMM2: O[16q x 64d] += P · V   (read chunk (ks*4+g)^x7)
#pragma unroll
        for (int ks = 0; ks < 2; ++ks) {
            s16x8 pa = *(const s16x8*)&s_pw[lm * 64 + (((ks * 4 + g) ^ x7) << 3)];
#pragma unroll
            for (int df = 0; df < 4; ++df) {
                const unsigned short* svr = svB + (df * 16 + lm) * 64;
                s16x8 vb = *(const s16x8*)(svr + (((ks * 4 + g) ^ x7) << 3));
                o_acc[df] = __builtin_amdgcn_mfma_f32_16x16x32_bf16(pa, vb, o_acc[df], 0, 0, 0);
            }
        }

        // single barrier per step: protects buf^1 reuse AND drains the
        // prefetch (which has had the whole compute phase to land)
        if (t < 9) __syncthreads();
    }
    // note: k in [577,640) contributes m=0, V^T=0 -> only +63*eps on rs (negligible)

    // ---- total row sum for q = q0w+lm: combine the 4 quad partials
    float tot = rs;
    tot += __shfl_xor(tot, 16, 64);
    tot += __shfl_xor(tot, 32, 64);
    float inv = (tot > 0.0f) ? 1.0f / tot : 0.0f;

    // ---- epilogue: rows q = q0w + g*4 + r; fetch inv from lane (g*4+r)
#pragma unroll
    for (int r = 0; r < 4; ++r) {
        int   qrow  = q0w + g * 4 + r;
        float inv_r = __shfl(inv, g * 4 + r, 64);
        if (qrow < Lq) {
            size_t base = ((size_t)((b * Lq + qrow) * NH + h)) * DD;
#pragma unroll
            for (int df = 0; df < 4; ++df) {
                float val = o_acc[df][r] * inv_r;
                if constexpr (F32)
                    ((float*)Og)[base + df * 16 + lm] = val;
                else
                    ((unsigned short*)Og)[base + df * 16 + lm] = (unsigned short)f2bf(val);
            }
        }
    }
}

__global__ __launch_bounds__(256, 4)
void fused_topo_attn(const void* __restrict__ Qg,
                     const unsigned short* __restrict__ Kp,
                     const unsigned short* __restrict__ Vt,
                     const unsigned short* __restrict__ Mm,
                     void* __restrict__ Og) {
    // 40,960 B total = 160KB/4 exactly -> 4 blocks/CU
    __shared__ __align__(16) unsigned short s_k[2 * 64 * 64];   // 16384 B (dbuf, swizzled)
    __shared__ __align__(16) unsigned short s_vt[2 * 64 * 64];  // 16384 B (dbuf, swizzled)
    __shared__ __align__(16) unsigned short s_p[4 * 16 * 64];   //  8192 B (XOR-swz, no pad)

    if (probe_f32(Qg)) attn_body<true>(Qg, Kp, Vt, Mm, Og, s_k, s_vt, s_p);
    else               attn_body<false>(Qg, Kp, Vt, Mm, Og, s_k, s_vt, s_p);
}

extern "C" void kernel_launch(void* const* d_in, const int* in_sizes, int n_in,
                              void* d_out, int out_size, void* d_ws, size_t ws_size,
                              hipStream_t stream) {
    (void)in_sizes; (void)n_in; (void)out_size; (void)ws_size;
    unsigned short* Kp = (unsigned short*)d_ws;
    unsigned short* Vt = (unsigned short*)((char*)d_ws + VT_OFF);
    unsigned short* Mm = (unsigned short*)((char*)d_ws + MM_OFF);

    // one fused prep launch: all three roles independent -> run concurrently
    prep_all<<<PK_BLOCKS + PVT_BLOCKS + PM_BLOCKS, 256, 0, stream>>>(
        d_in[0], d_in[1], d_in[2], d_in[3], Kp, Vt, Mm);
    fused_topo_attn<<<960, 256, 0, stream>>>(d_in[0], Kp, Vt, Mm, d_out);
}

// Round 5
// 123.943 us; speedup vs baseline: 1.0531x; 1.0236x over previous
//
#include <hip/hip_runtime.h>

// Fused kernelized attention w/ Toeplitz topological mask, MI355X gfx950.
// B=8 H=12 L=577 (24x24 grid + CLS) D=64, fp32 I/O (runtime-probed vs bf16).
//
// out[b,q,h,:] = sum_k p(q,k) v[k,:] / sum_k p(q,k)
//   p = (relu(q)/8+eps)·(relu(k)+eps) * |mask(h,q,k)| + eps
//
// R9: LDS-pipe cuts, keeping the R8 staging/barrier skeleton.
//  - GEMM2 A-operand taken DIRECTLY from GEMM1's transposed C-frags via
//    16x16x16 MFMA (A-frag layout A[row=lm][k=g*4+j] == sf[cf][j] exactly).
//    P LDS round-trip deleted; s_p buffer deleted (LDS 40960 -> 32768 B).
//  - V^T global image now carries an 8B-chunk XOR swizzle (c8 ^= d&15) baked
//    in by prep, so main's V staging is linear-source global_load_lds and the
//    GEMM2 b64 B-frag reads are bank-uniform (4 words/bank = wave64 minimum).
//  - Tail: step 9 (k=576..639, 1 valid row) peeled to a cf=0-only mini-step.
//  - Unchanged: K' path (16B XOR swizzle + b128 GEMM1 reads), M per-lane regs
//    ping-ponged, h-major XCD slot map, 1 barrier/step, dbuf LDS, hand-RNE
//    f2bf (R7 lesson: v_cvt_pk_bf16_f32 rounding is not RNE -> fails check).

#define Lq 577
#define NH 12
#define NB 8
#define DD 64
#define PAR 2304
#define EPSf 1e-8f

// workspace layout (bytes)
#define VT_OFF 7090176ull     // K' = 3,545,088 elem * 2B
#define MM_OFF 14954496ull    // + V^T = 8*12*64*640*2 = 7,864,320
                              // + M   = 12*577*640*2  = 8,862,720  (total 23.8 MB)

// fused prep grid partition
#define PK_BLOCKS  1731       // K':  1731 * 2048 elems = |K|
#define PVT_BLOCKS 960        // V^T: 10 kt * 12 h * 8 b
#define PM_BLOCKS  2316       // M:   12 h * 193 (3 q-rows per block)

typedef __attribute__((ext_vector_type(4))) float f32x4;
typedef __attribute__((ext_vector_type(8))) short s16x8;
typedef __attribute__((ext_vector_type(4))) short s16x4;

__device__ __forceinline__ float bflo(unsigned int u) {
    return __builtin_bit_cast(float, u << 16);
}
__device__ __forceinline__ float bfhi(unsigned int u) {
    return __builtin_bit_cast(float, u & 0xffff0000u);
}
// float -> bf16 round-to-nearest-even. NOTE (R7 lesson): do NOT replace with
// inline-asm v_cvt_pk_bf16_f32 — its rounding differs (biased), broke the
// post-timing check at 4.7e-2.
__device__ __forceinline__ unsigned int f2bf(float f) {
    unsigned int x = __builtin_bit_cast(unsigned int, f);
    return (x + 0x7fffu + ((x >> 16) & 1u)) >> 16;
}
__device__ __forceinline__ int imin(int a, int b) { return a < b ? a : b; }

// K=16 bf16 MFMA; A comes straight from the transposed GEMM1 C-frags.
__device__ __forceinline__ f32x4 mfma16(s16x4 a, s16x4 b, f32x4 c) {
#if __has_builtin(__builtin_amdgcn_mfma_f32_16x16x16bf16_1k)
    return __builtin_amdgcn_mfma_f32_16x16x16bf16_1k(a, b, c, 0, 0, 0);
#else
    // zero-padded K=32 fallback: slots (g, j<4) carry the data in BOTH
    // operands -> contraction identical to K=16.
    s16x8 az = {a[0], a[1], a[2], a[3], 0, 0, 0, 0};
    s16x8 bz = {b[0], b[1], b[2], b[3], 0, 0, 0, 0};
    return __builtin_amdgcn_mfma_f32_16x16x32_bf16(az, bz, c, 0, 0, 0);
#endif
}

// async global->LDS, 16B per lane; lds dest = wave-uniform base + lane*16
__device__ __forceinline__ void gload_lds16(const unsigned short* g, unsigned short* l) {
    __builtin_amdgcn_global_load_lds(
        (const __attribute__((address_space(1))) unsigned int*)g,
        (__attribute__((address_space(3))) unsigned int*)l, 16, 0, 0);
}

// per-wave dtype probe: fp32 N(0,1) lands in (2^-12, 64); bf16-pair
// reinterpretation lands at ~2^+-100 / denormal. Works for partial waves.
__device__ __forceinline__ bool probe_f32(const void* Qg) {
    float x = fabsf(((const float*)Qg)[threadIdx.x]);
    unsigned long long hit = __ballot(x > 2.44140625e-4f && x < 64.0f);
    unsigned long long act = __ballot(1);
    return 2 * __popcll(hit) >= __popcll(act);
}

// 8 consecutive elements -> float, dtype-templated
template <bool F32>
__device__ __forceinline__ void load8f(const void* G, size_t eidx, float* o) {
    if constexpr (F32) {
        const float* p = (const float*)G + eidx;
        float4 a = *(const float4*)p;
        float4 b = *(const float4*)(p + 4);
        o[0] = a.x; o[1] = a.y; o[2] = a.z; o[3] = a.w;
        o[4] = b.x; o[5] = b.y; o[6] = b.z; o[7] = b.w;
    } else {
        const unsigned short* p = (const unsigned short*)G + eidx;
        uint4 a = *(const uint4*)p;
        unsigned int u[4] = {a.x, a.y, a.z, a.w};
#pragma unroll
        for (int j = 0; j < 4; ++j) {
            o[2 * j]     = bflo(u[j]);
            o[2 * j + 1] = bfhi(u[j]);
        }
    }
}

// ---------------- fused prep kernel: K' | V^T | M, split by blockIdx range
template <bool F32>
__device__ void prep_all_body(const void* __restrict__ Kg,
                              const void* __restrict__ Vg,
                              const void* __restrict__ Tg,
                              unsigned short* __restrict__ Kp,
                              unsigned short* __restrict__ Vt,
                              unsigned short* __restrict__ Mm,
                              unsigned short* s) {
    const int bid = blockIdx.x;
    const int t   = threadIdx.x;

    if (bid < PK_BLOCKS) {
        // ---- role 1: K' = bf16(relu(K)+eps), layout [b,k,h,d]
        size_t i8 = ((size_t)bid * 256 + t) * 8;
        float f[8];
        load8f<F32>(Kg, i8, f);
        unsigned int o[4];
#pragma unroll
        for (int j = 0; j < 4; ++j) {
            unsigned int lo = f2bf(fmaxf(f[2 * j], 0.0f) + EPSf);
            unsigned int hi = f2bf(fmaxf(f[2 * j + 1], 0.0f) + EPSf);
            o[j] = lo | (hi << 16);
        }
        *(uint4*)(Kp + i8) = make_uint4(o[0], o[1], o[2], o[3]);

    } else if (bid < PK_BLOCKS + PVT_BLOCKS) {
        // ---- role 2: V^T bf16 [b,h,d,640], zeros past k=576.
        // Within each 64-col tile, 8B chunk c8 stored at (c8 ^ (d&15)):
        // makes main's GEMM2 b64 B-frag reads bank-uniform.
        int r  = bid - PK_BLOCKS;
        int kt = r % 10; r /= 10;
        int h  = r % NH;
        int b  = r / NH;
        {
            int kl  = t >> 2;              // 0..63
            int dch = (t & 3) * 16;
            int k   = kt * 64 + kl;
            unsigned int pk[8] = {};
            if (k <= 576) {
                float f[16];
                size_t base = ((size_t)((b * Lq + k) * NH + h)) * DD + dch;
                load8f<F32>(Vg, base, f);
                load8f<F32>(Vg, base + 8, f + 8);
#pragma unroll
                for (int j = 0; j < 8; ++j)
                    pk[j] = f2bf(f[2 * j]) | (f2bf(f[2 * j + 1]) << 16);
            }
#pragma unroll
            for (int j = 0; j < 8; ++j)
                *(unsigned int*)&s[kl * 72 + dch + 2 * j] = pk[j];
        }
        __syncthreads();
        {
            int d   = t >> 2;
            int kch = (t & 3) * 16;
            unsigned int o[8];
#pragma unroll
            for (int j = 0; j < 8; ++j) {
                unsigned short v0 = s[(kch + 2 * j) * 72 + d];
                unsigned short v1 = s[(kch + 2 * j + 1) * 72 + d];
                o[j] = (unsigned int)v0 | ((unsigned int)v1 << 16);
            }
            size_t rowbase = ((size_t)((b * NH + h) * 64 + d)) * 640 + kt * 64;
            int swz = d & 15;
#pragma unroll
            for (int i = 0; i < 4; ++i) {
                int c8 = (kch >> 2) + i;            // logical 8B chunk 0..15
                *(uint2*)(Vt + rowbase + (size_t)((c8 ^ swz) << 2)) =
                    make_uint2(o[2 * i], o[2 * i + 1]);
            }
        }

    } else {
        // ---- role 3: M = |toeplitz mask| bf16 [h,q,640]; 3 q-rows / block
        int r  = bid - (PK_BLOCKS + PVT_BLOCKS);
        int h  = r / 193;
        int qb = (r % 193) * 3;
        if (t < 240) {
            int q = qb + t / 80;
            if (q < Lq) {
                int k0 = (t % 80) * 8;
                int cq = 0;
                if (q > 0) {
                    int qq = q - 1;
                    int qi = (qq * 2731) >> 16;           // floor(qq/24)
                    cq = qq + 24 * qi + 1176;
                }
                unsigned int o[4];
#pragma unroll
                for (int j = 0; j < 4; ++j) {
                    unsigned int hv[2];
#pragma unroll
                    for (int e = 0; e < 2; ++e) {
                        int k = k0 + 2 * j + e;
                        float m;
                        if (k > 576) m = 0.0f;
                        else if (k == 0 || q == 0) m = 1.0f;
                        else {
                            int kk = k - 1;
                            int ki = (kk * 2731) >> 16;
                            int idx = cq - (kk + 24 * ki);
                            float pv = F32 ? ((const float*)Tg)[h * PAR + idx]
                                           : bflo((unsigned int)((const unsigned short*)Tg)[h * PAR + idx]);
                            m = fabsf(pv);
                            m = (m == m) ? m : 0.0f;
                        }
                        hv[e] = f2bf(m);
                    }
                    o[j] = hv[0] | (hv[1] << 16);
                }
                *(uint4*)(Mm + (size_t)(h * Lq + q) * 640 + k0) = make_uint4(o[0], o[1], o[2], o[3]);
            }
        }
    }
}
__global__ __launch_bounds__(256)
void prep_all(const void* __restrict__ Qg, const void* __restrict__ Kg,
              const void* __restrict__ Vg, const void* __restrict__ Tg,
              unsigned short* __restrict__ Kp, unsigned short* __restrict__ Vt,
              unsigned short* __restrict__ Mm) {
    __shared__ __align__(16) unsigned short s[64 * 72];   // used by role 2 only
    if (probe_f32(Qg)) prep_all_body<true>(Kg, Vg, Tg, Kp, Vt, Mm, s);
    else               prep_all_body<false>(Kg, Vg, Tg, Kp, Vt, Mm, s);
}

// ---------------- main kernel
template <bool F32>
__device__ void attn_body(const void* __restrict__ Qg,
                          const unsigned short* __restrict__ Kp,
                          const unsigned short* __restrict__ Vt,
                          const unsigned short* __restrict__ Mm,
                          void* __restrict__ Og,
                          unsigned short* s_k, unsigned short* s_vt) {
    const int tid  = threadIdx.x;
    const int w    = tid >> 6;
    const int lane = tid & 63;
    const int g    = lane >> 4;   // quad
    const int lm   = lane & 15;

    // h-major chunked XCD slot map (bid%8 = XCD under round-robin dispatch):
    //   slot chunks of 120 per XCD; h group = 80 contiguous slots (<=2 XCDs
    //   -> M ~1.3x HBM); (b,h) group = 10 contiguous slots, never crosses
    //   a 120-boundary (120%10==0) -> K'/V^T L2-local.
    const int bid  = blockIdx.x;
    const int slot = (bid & 7) * 120 + (bid >> 3);
    const int h    = slot / 80;
    const int rem  = slot - h * 80;
    const int b    = rem / 10;
    const int qt   = rem - b * 10;

    const int q0w = qt * 64 + w * 16;   // wave's first q row

    // ---- Q B-frags in registers: lane holds Q[q0w+lm][ds*32+g*8+j]
    const int q  = q0w + lm;
    const int qc = imin(q, Lq - 1);
    s16x8 a_q[2];
    {
        size_t rbase = ((size_t)((b * Lq + qc) * NH + h)) * DD;
#pragma unroll
        for (int ds = 0; ds < 2; ++ds) {
            float f[8];
            load8f<F32>(Qg, rbase + ds * 32 + g * 8, f);
            s16x8 a;
#pragma unroll
            for (int j = 0; j < 8; ++j) {
                float v = fmaf(fmaxf(f[j], 0.0f), 0.125f, EPSf);  // relu/8+eps
                a[j] = (short)f2bf(v);
            }
            a_q[ds] = a;
        }
    }

    // ---- staging lane constants
    const int r8 = lane >> 3;          // row within 8-row group
    const int c8 = lane & 7;           // 16B chunk within row
    const int xr = (c8 ^ r8) * 8;      // K': XOR-swizzled source chunk (elems)

    const unsigned short* KpBH = Kp + (size_t)b * (Lq * NH * DD) + h * DD;   // + k*768
    // V^T source is LINEAR (swizzle baked into the global image by prep)
    const unsigned short* VtL0 = Vt + ((size_t)(b * NH + h) * 64 + (w * 16 + r8)) * 640 + c8 * 8;
    const unsigned short* VtL1 = VtL0 + 8 * 640;
    // M row for THIS lane's q (per-lane register loads; 32B segments, L2-hot)
    const unsigned short* MmQ  = Mm + (size_t)h * (Lq * 640) + (size_t)qc * 640 + g * 4;

    f32x4 o_acc[4] = {};   // [df] C-frags: rows q_local=g*4+r, cols d=df*16+lm
    float rs = 0.0f;       // per-lane partial row sum for q (this quad's k subset)
    const int x7 = lm & 7; // K' fragment-read swizzle key

    // stage K'/V^T tile for column block kb into LDS buffer buf (4 x 1KB per wave)
    auto stageKV = [&](int kb, int buf) {
        unsigned short* skb = s_k  + buf * 4096 + (w * 16) * 64;
        unsigned short* svb = s_vt + buf * 4096 + (w * 16) * 64;
        int krr = kb + w * 16 + r8;
        int kr0 = imin(krr, Lq - 1);
        int kr1 = imin(krr + 8, Lq - 1);
        gload_lds16(KpBH + (size_t)kr0 * (NH * DD) + xr, skb);
        gload_lds16(KpBH + (size_t)kr1 * (NH * DD) + xr, skb + 8 * 64);
        gload_lds16(VtL0 + kb, svb);
        gload_lds16(VtL1 + kb, svb + 8 * 64);
    };

    // prologue: fill buffer 0; prime M ping-pong
    stageKV(0, 0);
    uint2 mu_n[4];
#pragma unroll
    for (int cf = 0; cf < 4; ++cf)
        mu_n[cf] = *(const uint2*)(MmQ + cf * 16);
    __syncthreads();   // drains vmcnt -> buf0 ready

    // ---- 9 full steps (k < 576); step 9 peeled as a mini-step below
    for (int t = 0; t < 9; ++t) {
        const int kb  = t * 64;
        const int buf = t & 1;

        uint2 mu[4];
#pragma unroll
        for (int cf = 0; cf < 4; ++cf) mu[cf] = mu_n[cf];

        // prefetch NEXT tile (incl. tile 9 for the mini-step) + next M rows
        stageKV(kb + 64, buf ^ 1);
#pragma unroll
        for (int cf = 0; cf < 4; ++cf)
            mu_n[cf] = *(const uint2*)(MmQ + kb + 64 + cf * 16);

        const unsigned short* skB = s_k  + buf * 4096;
        const unsigned short* svB = s_vt + buf * 4096;

        // ---- GEMM1 (transposed): S^T[64k x 16q] = K' · Q^T
        f32x4 sf[4];
#pragma unroll
        for (int cf = 0; cf < 4; ++cf) {
            const unsigned short* skr = skB + (cf * 16 + lm) * 64;
            int co = (g ^ x7) * 8;
            s16x8 kf0 = *(const s16x8*)(skr + co);
            s16x8 kf1 = *(const s16x8*)(skr + (co ^ 32));
            f32x4 acc = {};
            acc = __builtin_amdgcn_mfma_f32_16x16x32_bf16(kf0, a_q[0], acc, 0, 0, 0);
            acc = __builtin_amdgcn_mfma_f32_16x16x32_bf16(kf1, a_q[1], acc, 0, 0, 0);
            sf[cf] = acc;   // reg r: k = cf*16 + g*4 + r, q = q0w + lm
        }

        // ---- p = max(s,0)*m + eps; row-sum; pack to bf16 A-frags IN REGS.
        //      sf[cf][j] = P[k=cf*16+g*4+j][q=lm] == A-frag[q=lm][k] for K=16.
        s16x4 pa[4];
#pragma unroll
        for (int cf = 0; cf < 4; ++cf) {
            float m0 = bflo(mu[cf].x), m1 = bfhi(mu[cf].x);
            float m2 = bflo(mu[cf].y), m3 = bfhi(mu[cf].y);
            float p0 = fmaf(fmaxf(sf[cf][0], 0.0f), m0, EPSf);
            float p1 = fmaf(fmaxf(sf[cf][1], 0.0f), m1, EPSf);
            float p2 = fmaf(fmaxf(sf[cf][2], 0.0f), m2, EPSf);
            float p3 = fmaf(fmaxf(sf[cf][3], 0.0f), m3, EPSf);
            rs += (p0 + p1) + (p2 + p3);
            unsigned int d0 = f2bf(p0) | (f2bf(p1) << 16);
            unsigned int d1 = f2bf(p2) | (f2bf(p3) << 16);
            pa[cf] = __builtin_bit_cast(s16x4, make_uint2(d0, d1));
        }

        // ---- GEMM2: O[16q x 64d] += P · V  (K=16 per MFMA, A from regs).
        //      B-frag: V^T row df*16+lm, 8B chunk (4cf+g)^lm (baked swizzle).
#pragma unroll
        for (int cf = 0; cf < 4; ++cf) {
#pragma unroll
            for (int df = 0; df < 4; ++df) {
                const unsigned short* svr =
                    svB + (df * 16 + lm) * 64 + (((4 * cf + g) ^ lm) << 2);
                s16x4 vb = __builtin_bit_cast(s16x4, *(const uint2*)svr);
                o_acc[df] = mfma16(pa[cf], vb, o_acc[df]);
            }
        }

        // single barrier per step: protects buf^1 reuse AND drains the
        // prefetch (which has had the whole compute phase to land)
        __syncthreads();
    }

    // ---- mini-step t=9 (buf 1): only k=576 is real (cf=0); staged rows
    // 592+ are clamped dups and M=0 there; V^T tile 9 is zero past col 0.
    {
        const unsigned short* skB = s_k  + 4096;
        const unsigned short* svB = s_vt + 4096;
        const unsigned short* skr = skB + lm * 64;
        int co = (g ^ x7) * 8;
        s16x8 kf0 = *(const s16x8*)(skr + co);
        s16x8 kf1 = *(const s16x8*)(skr + (co ^ 32));
        f32x4 acc = {};
        acc = __builtin_amdgcn_mfma_f32_16x16x32_bf16(kf0, a_q[0], acc, 0, 0, 0);
        acc = __builtin_amdgcn_mfma_f32_16x16x32_bf16(kf1, a_q[1], acc, 0, 0, 0);
        float m0 = bflo(mu_n[0].x), m1 = bfhi(mu_n[0].x);
        float m2 = bflo(mu_n[0].y), m3 = bfhi(mu_n[0].y);
        float p0 = fmaf(fmaxf(acc[0], 0.0f), m0, EPSf);
        float p1 = fmaf(fmaxf(acc[1], 0.0f), m1, EPSf);
        float p2 = fmaf(fmaxf(acc[2], 0.0f), m2, EPSf);
        float p3 = fmaf(fmaxf(acc[3], 0.0f), m3, EPSf);
        rs += (p0 + p1) + (p2 + p3);
        unsigned int d0 = f2bf(p0) | (f2bf(p1) << 16);
        unsigned int d1 = f2bf(p2) | (f2bf(p3) << 16);
        s16x4 pa0 = __builtin_bit_cast(s16x4, make_uint2(d0, d1));
#pragma unroll
        for (int df = 0; df < 4; ++df) {
            const unsigned short* svr =
                svB + (df * 16 + lm) * 64 + (((g ^ lm)) << 2);
            s16x4 vb = __builtin_bit_cast(s16x4, *(const uint2*)svr);
            o_acc[df] = mfma16(pa0, vb, o_acc[df]);
        }
    }

    // ---- total row sum for q = q0w+lm: combine the 4 quad partials
    float tot = rs;
    tot += __shfl_xor(tot, 16, 64);
    tot += __shfl_xor(tot, 32, 64);
    float inv = (tot > 0.0f) ? 1.0f / tot : 0.0f;

    // ---- epilogue: rows q = q0w + g*4 + r; fetch inv from lane (g*4+r)
#pragma unroll
    for (int r = 0; r < 4; ++r) {
        int   qrow  = q0w + g * 4 + r;
        float inv_r = __shfl(inv, g * 4 + r, 64);
        if (qrow < Lq) {
            size_t base = ((size_t)((b * Lq + qrow) * NH + h)) * DD;
#pragma unroll
            for (int df = 0; df < 4; ++df) {
                float val = o_acc[df][r] * inv_r;
                if constexpr (F32)
                    ((float*)Og)[base + df * 16 + lm] = val;
                else
                    ((unsigned short*)Og)[base + df * 16 + lm] = (unsigned short)f2bf(val);
            }
        }
    }
}

__global__ __launch_bounds__(256, 4)
void fused_topo_attn(const void* __restrict__ Qg,
                     const unsigned short* __restrict__ Kp,
                     const unsigned short* __restrict__ Vt,
                     const unsigned short* __restrict__ Mm,
                     void* __restrict__ Og) {
    // 32,768 B total -> comfortably 4 blocks/CU (wave-cap limited)
    __shared__ __align__(16) unsigned short s_k[2 * 64 * 64];   // 16384 B (dbuf, 16B-swz)
    __shared__ __align__(16) unsigned short s_vt[2 * 64 * 64];  // 16384 B (dbuf, 8B-swz)

    if (probe_f32(Qg)) attn_body<true>(Qg, Kp, Vt, Mm, Og, s_k, s_vt);
    else               attn_body<false>(Qg, Kp, Vt, Mm, Og, s_k, s_vt);
}

extern "C" void kernel_launch(void* const* d_in, const int* in_sizes, int n_in,
                              void* d_out, int out_size, void* d_ws, size_t ws_size,
                              hipStream_t stream) {
    (void)in_sizes; (void)n_in; (void)out_size; (void)ws_size;
    unsigned short* Kp = (unsigned short*)d_ws;
    unsigned short* Vt = (unsigned short*)((char*)d_ws + VT_OFF);
    unsigned short* Mm = (unsigned short*)((char*)d_ws + MM_OFF);

    // one fused prep launch: all three roles independent -> run concurrently
    prep_all<<<PK_BLOCKS + PVT_BLOCKS + PM_BLOCKS, 256, 0, stream>>>(
        d_in[0], d_in[1], d_in[2], d_in[3], Kp, Vt, Mm);
    fused_topo_attn<<<960, 256, 0, stream>>>(d_in[0], Kp, Vt, Mm, d_out);
}